// Round 10
// baseline (481.651 us; speedup 1.0000x reference)
//
#include <hip/hip_runtime.h>

// LIF sim, three-phase:
//   0) split_h: pre-split h1 into bf16 hi/lo planes in d_ws, laid out as the
//      gemm's swizzled B-LDS image ([kt][nb] 8KB chunks).
//   1) lif_gemm<true>: aS = X @ H via bf16 4-way-split MFMA, f32 accumulate.
//      A-split via v_cvt_pk_bf16_f32 (RNE, bit-identical to bf16rne).
//      B staging = linear conflict-free 16B/lane copies. XCD-chunked swizzle.
//   2) lif_scan: verified 500-step LIF scan (f64 state), 20-step macro-blocks
//      with two 10-deep register banks (one vmcnt drain per 10 steps).
typedef __attribute__((ext_vector_type(8))) short short8;
typedef __attribute__((ext_vector_type(4))) float f32x4;

constexpr int BSZ = 256;
constexpr int NRN = 512;
constexpr int KIN = 512;
constexpr int TT  = 500;
constexpr int BM  = 128;   // m-tile (rows of x)
constexpr int BN  = 128;   // n-tile (neuron cols)
constexpr int KT  = 32;    // k-tile
constexpr int NBLK = (TT * BSZ / BM) * (NRN / BN);   // 4000
constexpr size_t WS_NEED = (size_t)2 * KIN * NRN * sizeof(unsigned short); // 1 MB

__device__ __forceinline__ unsigned short bf16rne(float f) {
    unsigned u = __float_as_uint(f);
    u += 0x7FFFu + ((u >> 16) & 1u);
    return (unsigned short)(u >> 16);
}
__device__ __forceinline__ float bf16f(unsigned short s) {
    return __uint_as_float(((unsigned)s) << 16);
}
// packed RNE bf16 pair: low16 = bf16(a), high16 = bf16(b). Bit-identical to bf16rne.
__device__ __forceinline__ unsigned cvtpk(float a, float b) {
    unsigned r;
    asm("v_cvt_pk_bf16_f32 %0, %1, %2" : "=v"(r) : "v"(a), "v"(b));
    return r;
}

// h1[k][n] -> hi/lo bf16 planes, laid out as the gemm's B-LDS image:
// chunk (kt*4+nb) of 8192 B; within: byte = ((nl*64+koct*16) ^ (((nl>>1)&3)<<4)) + 2*i
__global__ __launch_bounds__(512)
void split_h(const float* __restrict__ h1,
             unsigned short* __restrict__ wsH,
             unsigned short* __restrict__ wsL)
{
    const int k = blockIdx.x;          // 0..511
    const int n = threadIdx.x;         // 0..511 (coalesced read)
    const float v = h1[(size_t)k * NRN + n];
    const unsigned short h  = bf16rne(v);
    const unsigned short lo = bf16rne(v - bf16f(h));
    const int kt = k >> 5, koct = (k >> 3) & 3, i = k & 7;
    const int nb = n >> 7, nl = n & 127;
    const int byte = (kt * 4 + nb) * 8192 +
                     ((nl * 64 + koct * 16) ^ (((nl >> 1) & 3) << 4)) + i * 2;
    *reinterpret_cast<unsigned short*>((char*)wsH + byte) = h;
    *reinterpret_cast<unsigned short*>((char*)wsL + byte) = lo;
}

template<bool PS>
__global__ __launch_bounds__(256)
void lif_gemm(const float* __restrict__ x,
              const float* __restrict__ h1,
              const unsigned short* __restrict__ wsH,
              const unsigned short* __restrict__ wsL,
              float* __restrict__ out)
{
    // bf16 tiles, XOR-swizzled (byte ^= ((row>>1)&3)<<4): 4 x 8 KB = 32 KB
    __shared__ short AhS[BM * KT], AlS[BM * KT], BhS[BN * KT], BlS[BN * KT];

    const int tid  = threadIdx.x;
    const int l    = tid & 63;
    const int w    = tid >> 6;           // wave 0..3
    const int wm   = (w & 1) * 64;       // wave m-offset
    const int wn   = (w >> 1) * 64;      // wave n-offset
    const int lrow = l & 15;
    const int loct = l >> 4;             // k-octet 0..3

    // XCD-chunked bijective swizzle: 4000 = 8 x 500, 500 % 4 == 0 so the
    // 4 n-blocks of each m-tile stay inside one XCD's chunk (shared L2).
    const int nid = (blockIdx.x & 7) * (NBLK / 8) + (blockIdx.x >> 3);
    const size_t m0 = (size_t)(nid >> 2) * BM;
    const int    nb = nid & 3;
    const int    n0 = nb * BN;

    f32x4 acc[4][4];
    #pragma unroll
    for (int i = 0; i < 4; ++i)
        #pragma unroll
        for (int j = 0; j < 4; ++j) acc[i][j] = (f32x4)0.0f;

    for (int kt = 0; kt < KIN / KT; ++kt) {
        // ---- stage A: x[m0..m0+128][kt*32..+32] -> bf16 split via cvt_pk ----
        #pragma unroll
        for (int u4 = 0; u4 < 4; ++u4) {
            const int u = u4 * 256 + tid;         // 0..1023
            const int row = u >> 3, slot = u & 7; // row 0..127, float4 slot 0..7
            const float4 xv = *reinterpret_cast<const float4*>(
                x + (m0 + row) * KIN + kt * KT + slot * 4);
            // hi plane (RNE, bit-identical to bf16rne)
            const unsigned h01 = cvtpk(xv.x, xv.y);
            const unsigned h23 = cvtpk(xv.z, xv.w);
            // residuals: bf16f(lo16)=bits<<16, bf16f(hi16)=bits&0xFFFF0000
            const float r0 = xv.x - __uint_as_float(h01 << 16);
            const float r1v = xv.y - __uint_as_float(h01 & 0xFFFF0000u);
            const float r2 = xv.z - __uint_as_float(h23 << 16);
            const float r3 = xv.w - __uint_as_float(h23 & 0xFFFF0000u);
            const unsigned l01 = cvtpk(r0, r1v);
            const unsigned l23 = cvtpk(r2, r3);
            const unsigned long long hb = (unsigned long long)h01 | ((unsigned long long)h23 << 32);
            const unsigned long long lb = (unsigned long long)l01 | ((unsigned long long)l23 << 32);
            const int byte = (row * 64 + slot * 8) ^ (((row >> 1) & 3) << 4);
            *reinterpret_cast<unsigned long long*>((char*)AhS + byte) = hb;
            *reinterpret_cast<unsigned long long*>((char*)AlS + byte) = lb;
        }
        // ---- stage B ----
        if (PS) {
            // linear conflict-free copy: 16B/lane consecutive
            const float4* sH = reinterpret_cast<const float4*>(
                (const char*)wsH + (kt * 4 + nb) * 8192);
            const float4* sL = reinterpret_cast<const float4*>(
                (const char*)wsL + (kt * 4 + nb) * 8192);
            float4* dH = reinterpret_cast<float4*>(BhS);
            float4* dL = reinterpret_cast<float4*>(BlS);
            dH[tid]       = sH[tid];
            dH[256 + tid] = sH[256 + tid];
            dL[tid]       = sL[tid];
            dL[256 + tid] = sL[256 + tid];
        } else {
            #pragma unroll
            for (int u2 = 0; u2 < 2; ++u2) {
                const int u = u2 * 256 + tid;          // 0..511
                const int nl = u & 127, koct = u >> 7; // n-local, k-octet
                short8 hh, hl;
                #pragma unroll
                for (int i = 0; i < 8; ++i) {          // coalesced across nl
                    const float v = h1[(size_t)(kt * KT + koct * 8 + i) * NRN + n0 + nl];
                    const unsigned short h = bf16rne(v);
                    hh[i] = (short)h;
                    hl[i] = (short)bf16rne(v - bf16f(h));
                }
                const int byte = (nl * 64 + koct * 16) ^ (((nl >> 1) & 3) << 4);
                *reinterpret_cast<short8*>((char*)BhS + byte) = hh;
                *reinterpret_cast<short8*>((char*)BlS + byte) = hl;
            }
        }
        __syncthreads();

        // ---- fragment loads (ds_read_b128) ----
        short8 ah[4], al[4], bh[4], bl[4];
        #pragma unroll
        for (int mi = 0; mi < 4; ++mi) {
            const int row  = wm + mi * 16 + lrow;
            const int byte = (row * 64 + loct * 16) ^ (((row >> 1) & 3) << 4);
            ah[mi] = *reinterpret_cast<const short8*>((const char*)AhS + byte);
            al[mi] = *reinterpret_cast<const short8*>((const char*)AlS + byte);
        }
        #pragma unroll
        for (int ni = 0; ni < 4; ++ni) {
            const int nn   = wn + ni * 16 + lrow;
            const int byte = (nn * 64 + loct * 16) ^ (((nn >> 1) & 3) << 4);
            bh[ni] = *reinterpret_cast<const short8*>((const char*)BhS + byte);
            bl[ni] = *reinterpret_cast<const short8*>((const char*)BlS + byte);
        }

        // ---- 64 MFMA: 4 split products accumulate into same acc ----
        #pragma unroll
        for (int mi = 0; mi < 4; ++mi)
            #pragma unroll
            for (int ni = 0; ni < 4; ++ni) {
                acc[mi][ni] = __builtin_amdgcn_mfma_f32_16x16x32_bf16(ah[mi], bh[ni], acc[mi][ni], 0, 0, 0);
                acc[mi][ni] = __builtin_amdgcn_mfma_f32_16x16x32_bf16(ah[mi], bl[ni], acc[mi][ni], 0, 0, 0);
                acc[mi][ni] = __builtin_amdgcn_mfma_f32_16x16x32_bf16(al[mi], bh[ni], acc[mi][ni], 0, 0, 0);
                acc[mi][ni] = __builtin_amdgcn_mfma_f32_16x16x32_bf16(al[mi], bl[ni], acc[mi][ni], 0, 0, 0);
            }
        __syncthreads();
    }

    // ---- epilogue: C/D layout col=lane&15, row=(lane>>4)*4+j (m89-verified) ----
    #pragma unroll
    for (int mi = 0; mi < 4; ++mi)
        #pragma unroll
        for (int j = 0; j < 4; ++j) {
            const size_t row = m0 + wm + mi * 16 + loct * 4 + j;
            float* op = out + row * NRN + n0 + wn + lrow;
            #pragma unroll
            for (int ni = 0; ni < 4; ++ni)
                op[ni * 16] = acc[mi][ni][j];
        }
}

__global__ __launch_bounds__(512, 2)
void lif_scan(const float* __restrict__ r1,
              float* __restrict__ out)
{
    __shared__ unsigned long long smask[2][8];   // ping-pong 512-bit spike mask

    const int n  = threadIdx.x;      // neuron
    const int b  = blockIdx.x;       // batch row
    const int wv = n >> 6;
    const int ln = n & 63;
    const size_t row = (size_t)b * NRN + n;
    constexpr size_t STEP = (size_t)BSZ * NRN;

    if (n < 16) ((unsigned long long*)smask)[n] = 0ULL;

    // f64 ascending-j column sum of r1 (dense recurrent fast path)
    double csum = 0.0;
    for (int j = 0; j < KIN; ++j)
        csum += (double)r1[(size_t)j * NRN + n];

    double V = 1.0, Is = 0.0, Ir = 0.0, cnt = 0.0;
    const double steady = 0.01 * (double)n;
    constexpr double kS = 0.1, kN = 0.05, DT = 0.001;

    float bank0[10], bank1[10];
    #pragma unroll
    for (int i = 0; i < 10; ++i) bank0[i] = out[(size_t)i * STEP + row];
    __syncthreads();

    // One step: consumes AREG (aS), leaves spike float back in AREG.
#define LIF_STEP_R(T, AREG)                                                   \
    {                                                                         \
        const int t_ = (T);                                                   \
        const int p_ = t_ & 1;                                                \
        unsigned long long mw[8];                                             \
        int pc = 0;                                                           \
        _Pragma("unroll")                                                     \
        for (int w = 0; w < 8; ++w) { mw[w] = smask[p_][w]; pc += __popcll(mw[w]); } \
        double aR;                                                            \
        if (pc == 512) {                                                      \
            aR = csum;                                                        \
        } else if (pc == 0) {                                                 \
            aR = 0.0;                                                         \
        } else {                                                              \
            aR = 0.0;                                                         \
            _Pragma("unroll")                                                 \
            for (int w = 0; w < 8; ++w) {                                     \
                unsigned long long m_ = mw[w];                                \
                while (m_) {                          /* ascending j */       \
                    const int j = w * 64 + __builtin_ctzll(m_);               \
                    aR += (double)r1[(size_t)j * NRN + n];                    \
                    m_ &= m_ - 1;                                             \
                }                                                             \
            }                                                                 \
        }                                                                     \
        Is = Is - kS * Is + (double)(AREG);            /* gain_syn = 1 */     \
        Ir = Ir - kS * Ir + 0.5 * aR;                  /* gain_syn_rec */     \
        double Vn = V - kN * V + DT * (Is + Ir + steady);                     \
        Vn = fmax(Vn, 0.0);                                                   \
        const bool sp = (Vn - 1.0) > 0.0;                                     \
        cnt = sp ? 2.0 : (cnt - 1.0);                  /* REFR = 2 */         \
        V = sp ? 0.0 : ((cnt <= 0.0) ? Vn : 0.0);                             \
        (AREG) = sp ? 1.0f : 0.0f;                                            \
        const unsigned long long bal = __ballot(sp);                          \
        if (ln == 0) smask[p_ ^ 1][wv] = bal;                                 \
        __syncthreads();                                                      \
    }

    for (int blk = 0; blk < TT; blk += 20) {
        // issue next-half loads (blk+10..blk+19; blk<=480 so max t=499)
        #pragma unroll
        for (int i = 0; i < 10; ++i)
            bank1[i] = out[(size_t)(blk + 10 + i) * STEP + row];
        // steps blk..blk+9 on bank0 (first barrier drains the loads above)
        #pragma unroll
        for (int i = 0; i < 10; ++i) LIF_STEP_R(blk + i, bank0[i])
        // batched spike stores
        #pragma unroll
        for (int i = 0; i < 10; ++i)
            out[(size_t)(blk + i) * STEP + row] = bank0[i];
        // issue loads for next block's first half (guarded, uniform)
        if (blk + 20 < TT) {
            #pragma unroll
            for (int i = 0; i < 10; ++i)
                bank0[i] = out[(size_t)(blk + 20 + i) * STEP + row];
        }
        // steps blk+10..blk+19 on bank1
        #pragma unroll
        for (int i = 0; i < 10; ++i) LIF_STEP_R(blk + 10 + i, bank1[i])
        #pragma unroll
        for (int i = 0; i < 10; ++i)
            out[(size_t)(blk + 10 + i) * STEP + row] = bank1[i];
    }
#undef LIF_STEP_R
}

extern "C" void kernel_launch(void* const* d_in, const int* in_sizes, int n_in,
                              void* d_out, int out_size, void* d_ws, size_t ws_size,
                              hipStream_t stream) {
    const float* x  = (const float*)d_in[0];
    const float* h1 = (const float*)d_in[1];
    const float* r1 = (const float*)d_in[2];
    float* out = (float*)d_out;
    (void)in_sizes; (void)n_in; (void)out_size;

    if (ws_size >= WS_NEED) {
        unsigned short* wsH = (unsigned short*)d_ws;
        unsigned short* wsL = wsH + (size_t)KIN * NRN;
        split_h<<<dim3(KIN), dim3(NRN), 0, stream>>>(h1, wsH, wsL);
        lif_gemm<true><<<dim3(NBLK), dim3(256), 0, stream>>>(x, h1, wsH, wsL, out);
    } else {
        lif_gemm<false><<<dim3(NBLK), dim3(256), 0, stream>>>(x, h1, nullptr, nullptr, out);
    }
    lif_scan<<<dim3(BSZ), dim3(512), 0, stream>>>(r1, out);
}

// Round 11
// 399.382 us; speedup vs baseline: 1.2060x; 1.2060x over previous
//
#include <hip/hip_runtime.h>

// LIF sim, three-phase:
//   0) split_h: pre-split h1 into bf16 hi/lo planes in d_ws, laid out as the
//      gemm's swizzled B-LDS image ([kt][nb] 8KB chunks).
//   1) lif_gemm<true>: aS = X @ H via bf16 3-product-split MFMA
//      (xh·hh + xh·hl + xl·hh; xl·hl residual ~1e-4, below proven margins),
//      f32 accumulate, cvt_pk A-split, conflict-free B copy, XCD swizzle,
//      s_setprio(1) around the MFMA cluster.
//   2) lif_scan: verified 500-step LIF scan (f64 state), depth-4 prefetch
//      (Round-9 form — the macro-block variant regressed).
typedef __attribute__((ext_vector_type(8))) short short8;
typedef __attribute__((ext_vector_type(4))) float f32x4;

constexpr int BSZ = 256;
constexpr int NRN = 512;
constexpr int KIN = 512;
constexpr int TT  = 500;
constexpr int BM  = 128;   // m-tile (rows of x)
constexpr int BN  = 128;   // n-tile (neuron cols)
constexpr int KT  = 32;    // k-tile
constexpr int NBLK = (TT * BSZ / BM) * (NRN / BN);   // 4000
constexpr size_t WS_NEED = (size_t)2 * KIN * NRN * sizeof(unsigned short); // 1 MB

__device__ __forceinline__ unsigned short bf16rne(float f) {
    unsigned u = __float_as_uint(f);
    u += 0x7FFFu + ((u >> 16) & 1u);
    return (unsigned short)(u >> 16);
}
__device__ __forceinline__ float bf16f(unsigned short s) {
    return __uint_as_float(((unsigned)s) << 16);
}
// packed RNE bf16 pair: low16 = bf16(a), high16 = bf16(b). Bit-identical to bf16rne.
__device__ __forceinline__ unsigned cvtpk(float a, float b) {
    unsigned r;
    asm("v_cvt_pk_bf16_f32 %0, %1, %2" : "=v"(r) : "v"(a), "v"(b));
    return r;
}

// h1[k][n] -> hi/lo bf16 planes, laid out as the gemm's B-LDS image:
// chunk (kt*4+nb) of 8192 B; within: byte = ((nl*64+koct*16) ^ (((nl>>1)&3)<<4)) + 2*i
__global__ __launch_bounds__(512)
void split_h(const float* __restrict__ h1,
             unsigned short* __restrict__ wsH,
             unsigned short* __restrict__ wsL)
{
    const int k = blockIdx.x;          // 0..511
    const int n = threadIdx.x;         // 0..511 (coalesced read)
    const float v = h1[(size_t)k * NRN + n];
    const unsigned short h  = bf16rne(v);
    const unsigned short lo = bf16rne(v - bf16f(h));
    const int kt = k >> 5, koct = (k >> 3) & 3, i = k & 7;
    const int nb = n >> 7, nl = n & 127;
    const int byte = (kt * 4 + nb) * 8192 +
                     ((nl * 64 + koct * 16) ^ (((nl >> 1) & 3) << 4)) + i * 2;
    *reinterpret_cast<unsigned short*>((char*)wsH + byte) = h;
    *reinterpret_cast<unsigned short*>((char*)wsL + byte) = lo;
}

template<bool PS>
__global__ __launch_bounds__(256)
void lif_gemm(const float* __restrict__ x,
              const float* __restrict__ h1,
              const unsigned short* __restrict__ wsH,
              const unsigned short* __restrict__ wsL,
              float* __restrict__ out)
{
    // bf16 tiles, XOR-swizzled (byte ^= ((row>>1)&3)<<4): 4 x 8 KB = 32 KB
    __shared__ short AhS[BM * KT], AlS[BM * KT], BhS[BN * KT], BlS[BN * KT];

    const int tid  = threadIdx.x;
    const int l    = tid & 63;
    const int w    = tid >> 6;           // wave 0..3
    const int wm   = (w & 1) * 64;       // wave m-offset
    const int wn   = (w >> 1) * 64;      // wave n-offset
    const int lrow = l & 15;
    const int loct = l >> 4;             // k-octet 0..3

    // XCD-chunked bijective swizzle: 4000 = 8 x 500, 500 % 4 == 0 so the
    // 4 n-blocks of each m-tile stay inside one XCD's chunk (shared L2).
    const int nid = (blockIdx.x & 7) * (NBLK / 8) + (blockIdx.x >> 3);
    const size_t m0 = (size_t)(nid >> 2) * BM;
    const int    nb = nid & 3;
    const int    n0 = nb * BN;

    f32x4 acc[4][4];
    #pragma unroll
    for (int i = 0; i < 4; ++i)
        #pragma unroll
        for (int j = 0; j < 4; ++j) acc[i][j] = (f32x4)0.0f;

    for (int kt = 0; kt < KIN / KT; ++kt) {
        // ---- stage B (independent loads issue first, overlap A conversion) ----
        if (PS) {
            // linear conflict-free copy: 16B/lane consecutive
            const float4* sH = reinterpret_cast<const float4*>(
                (const char*)wsH + (kt * 4 + nb) * 8192);
            const float4* sL = reinterpret_cast<const float4*>(
                (const char*)wsL + (kt * 4 + nb) * 8192);
            float4* dH = reinterpret_cast<float4*>(BhS);
            float4* dL = reinterpret_cast<float4*>(BlS);
            dH[tid]       = sH[tid];
            dH[256 + tid] = sH[256 + tid];
            dL[tid]       = sL[tid];
            dL[256 + tid] = sL[256 + tid];
        } else {
            #pragma unroll
            for (int u2 = 0; u2 < 2; ++u2) {
                const int u = u2 * 256 + tid;          // 0..511
                const int nl = u & 127, koct = u >> 7; // n-local, k-octet
                short8 hh, hl;
                #pragma unroll
                for (int i = 0; i < 8; ++i) {          // coalesced across nl
                    const float v = h1[(size_t)(kt * KT + koct * 8 + i) * NRN + n0 + nl];
                    const unsigned short h = bf16rne(v);
                    hh[i] = (short)h;
                    hl[i] = (short)bf16rne(v - bf16f(h));
                }
                const int byte = (nl * 64 + koct * 16) ^ (((nl >> 1) & 3) << 4);
                *reinterpret_cast<short8*>((char*)BhS + byte) = hh;
                *reinterpret_cast<short8*>((char*)BlS + byte) = hl;
            }
        }
        // ---- stage A: x[m0..m0+128][kt*32..+32] -> bf16 split via cvt_pk ----
        #pragma unroll
        for (int u4 = 0; u4 < 4; ++u4) {
            const int u = u4 * 256 + tid;         // 0..1023
            const int row = u >> 3, slot = u & 7; // row 0..127, float4 slot 0..7
            const float4 xv = *reinterpret_cast<const float4*>(
                x + (m0 + row) * KIN + kt * KT + slot * 4);
            // hi plane (RNE, bit-identical to bf16rne)
            const unsigned h01 = cvtpk(xv.x, xv.y);
            const unsigned h23 = cvtpk(xv.z, xv.w);
            // residuals: bf16f(lo16)=bits<<16, bf16f(hi16)=bits&0xFFFF0000
            const float r0 = xv.x - __uint_as_float(h01 << 16);
            const float r1v = xv.y - __uint_as_float(h01 & 0xFFFF0000u);
            const float r2 = xv.z - __uint_as_float(h23 << 16);
            const float r3 = xv.w - __uint_as_float(h23 & 0xFFFF0000u);
            const unsigned l01 = cvtpk(r0, r1v);
            const unsigned l23 = cvtpk(r2, r3);
            const unsigned long long hb = (unsigned long long)h01 | ((unsigned long long)h23 << 32);
            const unsigned long long lb = (unsigned long long)l01 | ((unsigned long long)l23 << 32);
            const int byte = (row * 64 + slot * 8) ^ (((row >> 1) & 3) << 4);
            *reinterpret_cast<unsigned long long*>((char*)AhS + byte) = hb;
            *reinterpret_cast<unsigned long long*>((char*)AlS + byte) = lb;
        }
        __syncthreads();

        // ---- fragment loads (ds_read_b128) ----
        short8 ah[4], al[4], bh[4], bl[4];
        #pragma unroll
        for (int mi = 0; mi < 4; ++mi) {
            const int row  = wm + mi * 16 + lrow;
            const int byte = (row * 64 + loct * 16) ^ (((row >> 1) & 3) << 4);
            ah[mi] = *reinterpret_cast<const short8*>((const char*)AhS + byte);
            al[mi] = *reinterpret_cast<const short8*>((const char*)AlS + byte);
        }
        #pragma unroll
        for (int ni = 0; ni < 4; ++ni) {
            const int nn   = wn + ni * 16 + lrow;
            const int byte = (nn * 64 + loct * 16) ^ (((nn >> 1) & 3) << 4);
            bh[ni] = *reinterpret_cast<const short8*>((const char*)BhS + byte);
            bl[ni] = *reinterpret_cast<const short8*>((const char*)BlS + byte);
        }

        // ---- 48 MFMA: 3-product split (xl·hl dropped, ~1e-4 class) ----
        __builtin_amdgcn_s_setprio(1);
        #pragma unroll
        for (int mi = 0; mi < 4; ++mi)
            #pragma unroll
            for (int ni = 0; ni < 4; ++ni) {
                acc[mi][ni] = __builtin_amdgcn_mfma_f32_16x16x32_bf16(ah[mi], bh[ni], acc[mi][ni], 0, 0, 0);
                acc[mi][ni] = __builtin_amdgcn_mfma_f32_16x16x32_bf16(ah[mi], bl[ni], acc[mi][ni], 0, 0, 0);
                acc[mi][ni] = __builtin_amdgcn_mfma_f32_16x16x32_bf16(al[mi], bh[ni], acc[mi][ni], 0, 0, 0);
            }
        __builtin_amdgcn_s_setprio(0);
        __syncthreads();
    }

    // ---- epilogue: C/D layout col=lane&15, row=(lane>>4)*4+j (m89-verified) ----
    #pragma unroll
    for (int mi = 0; mi < 4; ++mi)
        #pragma unroll
        for (int j = 0; j < 4; ++j) {
            const size_t row = m0 + wm + mi * 16 + loct * 4 + j;
            float* op = out + row * NRN + n0 + wn + lrow;
            #pragma unroll
            for (int ni = 0; ni < 4; ++ni)
                op[ni * 16] = acc[mi][ni][j];
        }
}

__global__ __launch_bounds__(512, 2)
void lif_scan(const float* __restrict__ r1,
              float* __restrict__ out)
{
    __shared__ unsigned long long smask[2][8];   // ping-pong 512-bit spike mask

    const int n  = threadIdx.x;      // neuron
    const int b  = blockIdx.x;       // batch row
    const int wv = n >> 6;
    const int ln = n & 63;
    const size_t row = (size_t)b * NRN + n;
    constexpr size_t STEP = (size_t)BSZ * NRN;

    if (n < 16) ((unsigned long long*)smask)[n] = 0ULL;

    // f64 ascending-j column sum of r1 (dense recurrent fast path)
    double csum = 0.0;
    for (int j = 0; j < KIN; ++j)
        csum += (double)r1[(size_t)j * NRN + n];

    double V = 1.0, Is = 0.0, Ir = 0.0, cnt = 0.0;
    const double steady = 0.01 * (double)n;
    constexpr double kS = 0.1, kN = 0.05, DT = 0.001;

    // aS prefetch, depth 4 (named regs -> no scratch)
    float a0 = out[0 * STEP + row];
    float a1 = out[1 * STEP + row];
    float a2 = out[2 * STEP + row];
    float a3 = out[3 * STEP + row];
    __syncthreads();

#define LIF_STEP(T, AREG)                                                     \
    {                                                                         \
        const int t_ = (T);                                                   \
        const int p_ = t_ & 1;                                                \
        unsigned long long mw[8];                                             \
        int pc = 0;                                                           \
        _Pragma("unroll")                                                     \
        for (int w = 0; w < 8; ++w) { mw[w] = smask[p_][w]; pc += __popcll(mw[w]); } \
        double aR;                                                            \
        if (pc == 512) {                                                      \
            aR = csum;                                                        \
        } else if (pc == 0) {                                                 \
            aR = 0.0;                                                         \
        } else {                                                              \
            aR = 0.0;                                                         \
            _Pragma("unroll")                                                 \
            for (int w = 0; w < 8; ++w) {                                     \
                unsigned long long m_ = mw[w];                                \
                while (m_) {                          /* ascending j */       \
                    const int j = w * 64 + __builtin_ctzll(m_);               \
                    aR += (double)r1[(size_t)j * NRN + n];                    \
                    m_ &= m_ - 1;                                             \
                }                                                             \
            }                                                                 \
        }                                                                     \
        Is = Is - kS * Is + (double)(AREG);            /* gain_syn = 1 */     \
        Ir = Ir - kS * Ir + 0.5 * aR;                  /* gain_syn_rec */     \
        double Vn = V - kN * V + DT * (Is + Ir + steady);                     \
        Vn = fmax(Vn, 0.0);                                                   \
        const bool sp = (Vn - 1.0) > 0.0;                                     \
        cnt = sp ? 2.0 : (cnt - 1.0);                  /* REFR = 2 */         \
        V = sp ? 0.0 : ((cnt <= 0.0) ? Vn : 0.0);                             \
        out[(size_t)t_ * STEP + row] = sp ? 1.0f : 0.0f;                      \
        const unsigned long long bal = __ballot(sp);                          \
        if (ln == 0) smask[p_ ^ 1][wv] = bal;                                 \
        __syncthreads();                                                      \
    }

    for (int t4 = 0; t4 < TT; t4 += 4) {
        LIF_STEP(t4 + 0, a0)
        a0 = (t4 + 4 < TT) ? out[(size_t)(t4 + 4) * STEP + row] : 0.0f;
        LIF_STEP(t4 + 1, a1)
        a1 = (t4 + 5 < TT) ? out[(size_t)(t4 + 5) * STEP + row] : 0.0f;
        LIF_STEP(t4 + 2, a2)
        a2 = (t4 + 6 < TT) ? out[(size_t)(t4 + 6) * STEP + row] : 0.0f;
        LIF_STEP(t4 + 3, a3)
        a3 = (t4 + 7 < TT) ? out[(size_t)(t4 + 7) * STEP + row] : 0.0f;
    }
#undef LIF_STEP
}

extern "C" void kernel_launch(void* const* d_in, const int* in_sizes, int n_in,
                              void* d_out, int out_size, void* d_ws, size_t ws_size,
                              hipStream_t stream) {
    const float* x  = (const float*)d_in[0];
    const float* h1 = (const float*)d_in[1];
    const float* r1 = (const float*)d_in[2];
    float* out = (float*)d_out;
    (void)in_sizes; (void)n_in; (void)out_size;

    if (ws_size >= WS_NEED) {
        unsigned short* wsH = (unsigned short*)d_ws;
        unsigned short* wsL = wsH + (size_t)KIN * NRN;
        split_h<<<dim3(KIN), dim3(NRN), 0, stream>>>(h1, wsH, wsL);
        lif_gemm<true><<<dim3(NBLK), dim3(256), 0, stream>>>(x, h1, wsH, wsL, out);
    } else {
        lif_gemm<false><<<dim3(NBLK), dim3(256), 0, stream>>>(x, h1, nullptr, nullptr, out);
    }
    lif_scan<<<dim3(BSZ), dim3(512), 0, stream>>>(r1, out);
}